// Round 8
// baseline (225.413 us; speedup 1.0000x reference)
//
#include <hip/hip_runtime.h>

// TimeConcater: new_x[b,p,d] = sum_l [bucket(ts[b,l])==p] * x[b,l,d]
// B=32, L=4096, D=256, P=32 buckets over np.linspace(0,1.001,33) edges.
// Output flat: new_x (32,32,256), then time_steps (32,4096).
//
// R7: read-parallelism push. Evidence R2/R3/R6: three different algorithms
// all plateau at ~85-93 us (~1.5 TB/s effective) with every pipe idle ->
// latency-bound reads, capped by occupancy x outstanding-loads. Fix: split
// each (b,p) bucket 16 ways -> 4096 blocks / 16K waves (2x device wave
// capacity), zero LDS / zero barriers in the gather, 8-deep load unroll,
// acc in 8 VGPRs. Flush via native global f32 atomics (proven cheap R4-R6).
// LDS fp32 atomics remain banned (~209 cyc/wave-op, R0/R4/R5).

#define Bk 32
#define Lk 4096
#define Dk 256
#define Pk 32

__device__ __forceinline__ int bucket_of(float tv) {
    // Emulate np.linspace(0.0, 1.001, 33): edge(i) = float32((double)i * (1.001/32))
    const double step = 1.001 / 32.0;
    int p = (int)(tv * (float)(32.0 / 1.001));
    p = p < 0 ? 0 : (p > 31 ? 31 : p);
    while (p > 0 && tv < (float)((double)p * step)) --p;
    while (p < 31 && tv >= (float)((double)(p + 1) * step)) ++p;
    return p;
}

// ---- Phase A: per-batch counting sort of rows into buckets (R1, proven) ---
__global__ __launch_bounds__(512) void tc_bucketize(
        const float* __restrict__ ts,
        int* __restrict__ list,      // [B][L] row indices, bucket-contiguous
        int* __restrict__ bounds,    // [B][33] exclusive bucket offsets
        float* __restrict__ ts_out) {
    __shared__ int cnt[Pk];
    __shared__ int off[Pk];
    const int b = blockIdx.x;
    const int t = threadIdx.x;

    if (t < Pk) cnt[t] = 0;
    __syncthreads();

    int pv[8];
#pragma unroll
    for (int k = 0; k < 8; ++k) {
        const int l = t + k * 512;
        const float tv = ts[(size_t)b * Lk + l];
        ts_out[(size_t)b * Lk + l] = tv;          // passthrough output
        const int p = bucket_of(tv);
        pv[k] = p;
        atomicAdd(&cnt[p], 1);
    }
    __syncthreads();

    if (t == 0) {
        int s = 0;
        for (int p = 0; p < Pk; ++p) {
            off[p] = s;
            bounds[b * (Pk + 1) + p] = s;
            s += cnt[p];
        }
        bounds[b * (Pk + 1) + Pk] = s;            // == Lk
    }
    __syncthreads();

#pragma unroll
    for (int k = 0; k < 8; ++k) {
        const int l = t + k * 512;
        const int idx = atomicAdd(&off[pv[k]], 1);
        list[(size_t)b * Lk + idx] = l;
    }
}

// ---- Phase B: 16-way-split register gather, no LDS, no barriers ----------
// grid = (Pk, Bk, 4) x 256 threads. Wave (s*4+w) of block (p,b,s) owns a
// contiguous 1/16 segment of the bucket's row list.
__global__ __launch_bounds__(256, 6) void tc_gather(
        const float* __restrict__ x,
        const int* __restrict__ list,
        const int* __restrict__ bounds,
        float* __restrict__ out) {
    const int p = blockIdx.x;
    const int b = blockIdx.y;
    const int s = blockIdx.z;
    const int t = threadIdx.x;
    const int w = t >> 6;
    const int lane = t & 63;
    const int col4 = lane << 2;
    const int sidx = s * 4 + w;              // 0..15

    const int start = bounds[b * (Pk + 1) + p];
    const int cnt = bounds[b * (Pk + 1) + p + 1] - start;
    const int seg = (cnt + 15) >> 4;
    int i = start + sidx * seg;
    const int iend = min(i + seg, start + cnt);

    const float* xb = x + (size_t)b * Lk * Dk;
    const int* lb = list + (size_t)b * Lk;

    float4 a0 = make_float4(0.f, 0.f, 0.f, 0.f);
    float4 a1 = make_float4(0.f, 0.f, 0.f, 0.f);

    // 8-deep: 8 independent 1 KB global_load_dwordx4 in flight per wave.
    for (; i + 8 <= iend; i += 8) {
        int r[8];
#pragma unroll
        for (int j = 0; j < 8; ++j) r[j] = lb[i + j];
        float4 v[8];
#pragma unroll
        for (int j = 0; j < 8; ++j)
            v[j] = *(const float4*)(xb + (size_t)r[j] * Dk + col4);
#pragma unroll
        for (int j = 0; j < 8; j += 2) {
            a0.x += v[j].x;     a0.y += v[j].y;
            a0.z += v[j].z;     a0.w += v[j].w;
            a1.x += v[j + 1].x; a1.y += v[j + 1].y;
            a1.z += v[j + 1].z; a1.w += v[j + 1].w;
        }
    }
    for (; i < iend; ++i) {
        const float4 v = *(const float4*)(xb + (size_t)lb[i] * Dk + col4);
        a0.x += v.x; a0.y += v.y; a0.z += v.z; a0.w += v.w;
    }
    a0.x += a1.x; a0.y += a1.y; a0.z += a1.z; a0.w += a1.w;

    // Fire-and-forget native f32 atomics onto the zeroed output.
    float* op = out + ((size_t)b * Pk + p) * Dk + col4;
    unsafeAtomicAdd(&op[0], a0.x);
    unsafeAtomicAdd(&op[1], a0.y);
    unsafeAtomicAdd(&op[2], a0.z);
    unsafeAtomicAdd(&op[3], a0.w);
}

extern "C" void kernel_launch(void* const* d_in, const int* in_sizes, int n_in,
                              void* d_out, int out_size, void* d_ws, size_t ws_size,
                              hipStream_t stream) {
    const float* x  = (const float*)d_in[0];
    const float* ts = (const float*)d_in[1];
    float* out = (float*)d_out;
    float* ts_out = out + (size_t)Bk * Pk * Dk;

    int* list   = (int*)d_ws;                       // B*L ints = 512 KB
    int* bounds = list + (size_t)Bk * Lk;           // B*33 ints

    // Zero new_x region (gather atomics accumulate onto it).
    hipMemsetAsync(out, 0, (size_t)Bk * Pk * Dk * sizeof(float), stream);

    tc_bucketize<<<Bk, 512, 0, stream>>>(ts, list, bounds, ts_out);
    dim3 grid(Pk, Bk, 4);
    tc_gather<<<grid, 256, 0, stream>>>(x, list, bounds, out);
}

// Round 9
// 187.507 us; speedup vs baseline: 1.2022x; 1.2022x over previous
//
#include <hip/hip_runtime.h>

// TimeConcater: new_x[b,p,d] = sum_l [bucket(ts[b,l])==p] * x[b,l,d]
// B=32, L=4096, D=256, P=32 buckets over np.linspace(0,1.001,33) edges.
// Output flat: new_x (32,32,256), then time_steps (32,4096).
//
// R8: non-temporal loads. Evidence R2/R3/R6/R7: x-reads pin at ~1.5-1.7 TB/s
// across four different structures, invariant to occupancy/ILP/pattern ->
// per-CU L1 miss-concurrency cap. x has ZERO intra-kernel reuse, so bypass
// L1 entirely with __builtin_nontemporal_load (global_load_dwordx4 nt).
// Structure: R3's fused single kernel (ballot compaction, register gather,
// direct store — no global atomics, no memset), 8-deep load unroll,
// 24 waves/CU.

#define Bk 32
#define Lk 4096
#define Dk 256
#define Pk 32
#define NTH 512          // 8 waves per block
#define NW 8

typedef float v4f __attribute__((ext_vector_type(4)));

__device__ __forceinline__ int bucket_of(float tv) {
    // Emulate np.linspace(0.0, 1.001, 33): edge(i) = float32((double)i * (1.001/32))
    const double step = 1.001 / 32.0;
    int p = (int)(tv * (float)(32.0 / 1.001));
    p = p < 0 ? 0 : (p > 31 ? 31 : p);
    while (p > 0 && tv < (float)((double)p * step)) --p;
    while (p < 31 && tv >= (float)((double)(p + 1) * step)) ++p;
    return p;
}

__global__ __launch_bounds__(NTH, 6) void tc_fused(
        const float* __restrict__ x,
        const float* __restrict__ ts,
        float* __restrict__ out,
        float* __restrict__ ts_out) {
    __shared__ int rows[Lk];          // 16 KB worst case
    __shared__ int nrows;
    __shared__ v4f red[NW * 64];      // 8 KB cross-wave reduction

    const int p = blockIdx.x;
    const int b = blockIdx.y;
    const int t = threadIdx.x;
    const int w = t >> 6;             // wave 0..7
    const int lane = t & 63;
    const int col4 = lane << 2;

    if (t == 0) nrows = 0;
    __syncthreads();

    // Scan ts[b,:]; wave-aggregated compaction of matching row indices.
    const float* tsb = ts + (size_t)b * Lk;
#pragma unroll
    for (int k = 0; k < Lk / NTH; ++k) {
        const int l = t + k * NTH;
        const float tv = tsb[l];
        if (p == 0) ts_out[(size_t)b * Lk + l] = tv;
        const bool match = (bucket_of(tv) == p);
        const unsigned long long m = __ballot(match);
        const int nact = __popcll(m);
        int wbase = 0;
        if (lane == 0 && nact) wbase = atomicAdd(&nrows, nact);
        wbase = __shfl(wbase, 0);
        if (match) {
            const int pre = __popcll(m & ((1ull << lane) - 1ull));
            rows[wbase + pre] = l;
        }
    }
    __syncthreads();
    const int cnt = nrows;

    // Register gather, 8-deep NT loads (8 outstanding 1 KB dwordx4 nt).
    const float* xb = x + (size_t)b * Lk * Dk;
    v4f a0 = 0.f, a1 = 0.f, a2 = 0.f, a3 = 0.f;
    int i = w;
    for (; i + 7 * NW < cnt; i += 8 * NW) {
        int r[8];
#pragma unroll
        for (int j = 0; j < 8; ++j) r[j] = rows[i + j * NW];
        v4f v[8];
#pragma unroll
        for (int j = 0; j < 8; ++j)
            v[j] = __builtin_nontemporal_load(
                (const v4f*)(xb + (size_t)r[j] * Dk + col4));
        a0 += v[0]; a1 += v[1]; a2 += v[2]; a3 += v[3];
        a0 += v[4]; a1 += v[5]; a2 += v[6]; a3 += v[7];
    }
    for (; i < cnt; i += NW) {
        a0 += __builtin_nontemporal_load(
            (const v4f*)(xb + (size_t)rows[i] * Dk + col4));
    }
    a0 += a1; a2 += a3; a0 += a2;

    // Cross-wave reduce; wave 0 stores the final 1 KB output row directly.
    red[w * 64 + lane] = a0;
    __syncthreads();
    if (w == 0) {
        v4f r = red[lane];
#pragma unroll
        for (int ww = 1; ww < NW; ++ww) r += red[ww * 64 + lane];
        *(v4f*)(out + ((size_t)b * Pk + p) * Dk + col4) = r;
    }
}

extern "C" void kernel_launch(void* const* d_in, const int* in_sizes, int n_in,
                              void* d_out, int out_size, void* d_ws, size_t ws_size,
                              hipStream_t stream) {
    const float* x  = (const float*)d_in[0];
    const float* ts = (const float*)d_in[1];
    float* out = (float*)d_out;
    float* ts_out = out + (size_t)Bk * Pk * Dk;

    dim3 grid(Pk, Bk);   // one block per output row; direct store, no memset
    tc_fused<<<grid, NTH, 0, stream>>>(x, ts, out, ts_out);
}